// Round 1
// baseline (297.073 us; speedup 1.0000x reference)
//
#include <hip/hip_runtime.h>

// Guided filter, R=1, EPS=1e-6, (8,3,1024,1024) fp32 — streaming separable version.
//
// One wave = one strip: 64 lanes = 64 adjacent (clamped) columns, TH output rows.
// Lanes 0,1,62,63 are horizontal halo; lanes 2..61 emit 60 output columns.
// Per row iteration (all in registers, no LDS arrays, no syncthreads):
//   vertical 3-sums of {x,y,xy,xx}  -> horizontal 3-sums via __shfl
//   -> A,b (v_rcp_f32)              -> horizontal 3-sums of A,b via __shfl
//   -> 3-deep vertical history      -> res = (SA*x + SB)/9, trunc, clamp, store.
//
// Replication-pad semantics:
//  - columns: per-lane clamped load column gives exact windows for in-range
//    centers; A,b at the 2 out-of-range halo lanes of edge tiles are fixed by
//    copying from the adjacent lane (A(-1) == A(0)).
//  - rows: iterate the *clamped* center row cy = clamp(ty0+ly-1); saturation at
//    image top/bottom naturally duplicates the edge windows in the history.

#define TH 32   // output rows per wave-strip
#define OW 60   // output cols per wave (64 lanes - 4 halo)

__global__ __launch_bounds__(256) void gf_kernel(
    const float* __restrict__ xg, const float* __restrict__ yg,
    float* __restrict__ outg, int H, int W) {
  const int lane = threadIdx.x;            // 0..63, block = (64,4)
  const int img = blockIdx.z;
  const size_t ibase = (size_t)img * H * W;
  const float* __restrict__ xi = xg + ibase;
  const float* __restrict__ yi = yg + ibase;
  float* __restrict__ oi = outg + ibase;

  int tx0 = blockIdx.x * OW;
  if (tx0 > W - OW) tx0 = W - OW;          // last tile overlaps (idempotent writes)
  const int ty0 = (blockIdx.y * 4 + threadIdx.y) * TH;

  const int col = tx0 + lane - 2;          // this lane's (virtual) column
  const int gxc = min(max(col, 0), W - 1); // clamped load column
  const bool wok = (lane >= 2) && (lane < 62);

  // A/b fixup for out-of-range halo lanes on edge tiles: A(col -1) := A(col 0)
  const bool leftE = (tx0 == 0);
  const bool rightE = (tx0 + OW >= W);
  const bool needfix = leftE || rightE;
  int fixsrc = lane;
  if (leftE && lane == 1) fixsrc = 2;
  if (rightE && lane == 62) fixsrc = 61;

  const float inv9 = 1.0f / 9.0f;

  float hA0 = 0.f, hA1 = 0.f, hA2 = 0.f;   // horizontal sums of A at rows cy-2,cy-1,cy
  float hB0 = 0.f, hB1 = 0.f, hB2 = 0.f;

  auto step = [&](int ly, bool emit) {
    // clamped center row for this A-row; window rows clamp(cy-1), cy, clamp(cy+1)
    int cy = min(max(ty0 + ly - 1, 0), H - 1);
    int r0 = max(cy - 1, 0);
    int r2 = min(cy + 1, H - 1);
    const float* xr0 = xi + (size_t)r0 * W;
    const float* xr1 = xi + (size_t)cy * W;
    const float* xr2 = xi + (size_t)r2 * W;
    const float* yr0 = yi + (size_t)r0 * W;
    const float* yr1 = yi + (size_t)cy * W;
    const float* yr2 = yi + (size_t)r2 * W;
    float xa = xr0[gxc], xb = xr1[gxc], xc = xr2[gxc];
    float ya = yr0[gxc], yb = yr1[gxc], yc = yr2[gxc];

    // vertical 3-sums (per lane-column)
    float vx = xa + xb + xc;
    float vy = ya + yb + yc;
    float vxy = xa * ya + xb * yb + xc * yc;
    float vxx = xa * xa + xb * xb + xc * xc;

    // horizontal 3-sums across lanes
    float Sx  = __shfl_up(vx, 1)  + vx  + __shfl_down(vx, 1);
    float Sy  = __shfl_up(vy, 1)  + vy  + __shfl_down(vy, 1);
    float Sxy = __shfl_up(vxy, 1) + vxy + __shfl_down(vxy, 1);
    float Sxx = __shfl_up(vxx, 1) + vxx + __shfl_down(vxx, 1);

    // A = (9*Sxy - Sx*Sy) / (9*Sxx - Sx^2 + 81*eps);  b = mean_y - A*mean_x
    float num = 9.0f * Sxy - Sx * Sy;
    float den = 9.0f * Sxx - Sx * Sx + 8.1e-05f;  // always > 0 (Cauchy-Schwarz)
    float rden;
    asm("v_rcp_f32 %0, %1" : "=v"(rden) : "v"(den));
    float A = num * rden;
    float b = Sy * inv9 - A * (Sx * inv9);

    if (needfix) {  // wave-uniform branch; identity shuffle except 1 halo lane
      A = __shfl(A, fixsrc);
      b = __shfl(b, fixsrc);
    }

    // stage-3 horizontal 3-sums of A,b
    float hAn = __shfl_up(A, 1) + A + __shfl_down(A, 1);
    float hBn = __shfl_up(b, 1) + b + __shfl_down(b, 1);
    hA0 = hA1; hA1 = hA2; hA2 = hAn;
    hB0 = hB1; hB1 = hB2; hB2 = hBn;

    if (emit) {
      int gr = ty0 + ly - 2;               // output image row
      // x at (gr, col): r0 == gr except at the saturated bottom row (then cy == gr)
      float xv = (r0 == gr) ? xa : xb;
      float SA = hA0 + hA1 + hA2;
      float SB = hB0 + hB1 + hB2;
      float res = (SA * xv + SB) * inv9;
      float t = truncf(res);
      t = fminf(fmaxf(t, 0.0f), 255.0f);
      if (wok) oi[(size_t)gr * W + col] = t;
    }
  };

  step(0, false);
  step(1, false);
#pragma unroll 4
  for (int ly = 2; ly < TH + 2; ++ly) step(ly, true);
}

extern "C" void kernel_launch(void* const* d_in, const int* in_sizes, int n_in,
                              void* d_out, int out_size, void* d_ws, size_t ws_size,
                              hipStream_t stream) {
  const float* x = (const float*)d_in[0];
  const float* y = (const float*)d_in[1];
  float* out = (float*)d_out;
  const int H = 1024, W = 1024;
  const int imgs = in_sizes[0] / (H * W);  // 8*3 = 24
  dim3 block(64, 4, 1);
  dim3 grid((W + OW - 1) / OW, H / (TH * 4), imgs);
  gf_kernel<<<grid, block, 0, stream>>>(x, y, out, H, W);
}

// Round 2
// 266.839 us; speedup vs baseline: 1.1133x; 1.1133x over previous
//
#include <hip/hip_runtime.h>

// Guided filter, R=1, EPS=1e-6, (8,3,1024,1024) fp32 — packed-4 streaming version.
//
// One wave covers 256 columns (64 lanes x float4); lanes 1..62 emit 248 cols.
// Rolling 3-row register window + 1-step register prefetch: 2 vector loads per
// row-step (vs 6 scalar), 12 shuffles per step for 4 output columns (vs 12 for 1).
// Vertical replication (top/bottom) hoisted out of the hot loop as
// history-duplication steps; horizontal replication = clamped loads + A/b fixup
// shuffle on the two edge column-blocks.

typedef float f4 __attribute__((ext_vector_type(4)));

#define TH 32     // output rows per wave-strip
#define OWPB 248  // output cols per wave (lanes 1..62 x 4)

__global__ __launch_bounds__(256, 4) void gf_kernel(
    const float* __restrict__ xg, const float* __restrict__ yg,
    float* __restrict__ outg, int H, int W) {
  const int lane = threadIdx.x;  // block = (64,4)
  const int img = blockIdx.z;
  const size_t ibase = (size_t)img * H * W;
  const float* __restrict__ xi = xg + ibase;
  const float* __restrict__ yi = yg + ibase;
  float* __restrict__ oi = outg + ibase;

  int tx0 = blockIdx.x * OWPB;
  const int skipb = tx0;             // dedupe overlap writes of the clamped block
  if (tx0 > W - OWPB) tx0 = W - OWPB;
  const int ty0 = (blockIdx.y * 4 + threadIdx.y) * TH;

  const int c0 = tx0 - 4 + 4 * lane;           // first col of this lane's pack
  const bool inb = (c0 >= 0) && (c0 <= W - 4); // whole pack in-range?
  const int cbc = (c0 < 0) ? 0 : (W - 1);      // broadcast col for OOB edge lanes
  const bool wok = (lane >= 1) && (lane <= 62) && (c0 >= skipb);
  const bool leftE = (tx0 == 0);
  const bool rightE = (tx0 + OWPB >= W);
  const float inv9 = 1.0f / 9.0f;

  f4 xr0, xr1, xr2, yr0, yr1, yr2, xpf, ypf;   // rolling rows + prefetch
  f4 hA0, hA1, hA2, hA3, hB0, hB1, hB2, hB3;   // 4-slot history (renaming-friendly)
  int nextr;

  auto ldrow = [&](int r, f4& xv, f4& yv) {
    const float* xr = xi + (size_t)r * W;
    const float* yr = yi + (size_t)r * W;
    if (inb) {
      xv = *(const f4*)(xr + c0);
      yv = *(const f4*)(yr + c0);
    } else {  // only lane 0 / lane 63 on edge col-blocks: all 4 cols clamp to one
      float a = xr[cbc], b = yr[cbc];
      xv = (f4)(a);
      yv = (f4)(b);
    }
  };

  // horizontal 3-sum of a packed quantity: s[j] = v[j-1]+v[j]+v[j+1]
  auto hsum3 = [&](f4 v) {
    float vl = __shfl_up(v[3], 1);
    float vr = __shfl_down(v[0], 1);
    float a01 = v[0] + v[1], a12 = v[1] + v[2], a23 = v[2] + v[3];
    f4 s;
    s[0] = vl + a01;
    s[1] = a01 + v[2];
    s[2] = a12 + v[3];
    s[3] = a23 + vr;
    return s;
  };

  auto emit_row = [&](int ly, f4 xv) {
    f4 SA = hA1 + hA2 + hA3;
    f4 SB = hB1 + hB2 + hB3;
    f4 st;
#pragma unroll
    for (int j = 0; j < 4; ++j) {
      float res = (SA[j] * xv[j] + SB[j]) * inv9;
      float t = truncf(res);
      st[j] = fminf(fmaxf(t, 0.0f), 255.0f);
    }
    if (wok) {
      int gr = ty0 + ly - 2;
      __builtin_nontemporal_store(st, (f4*)(oi + (size_t)gr * W + c0));
    }
  };

  auto dup_hist = [&]() {  // push a duplicate of the newest A,b row (replication)
    hA0 = hA1; hA1 = hA2; hA2 = hA3;
    hB0 = hB1; hB1 = hB2; hB2 = hB3;
  };

  auto step_adv = [&](int ly, bool doemit, bool dopf) {
    xr0 = xr1; xr1 = xr2; xr2 = xpf;
    yr0 = yr1; yr1 = yr2; yr2 = ypf;
    if (dopf) {
      ldrow(nextr, xpf, ypf);
      nextr = min(nextr + 1, H - 1);
    }
    f4 vx = xr0 + xr1 + xr2;
    f4 vy = yr0 + yr1 + yr2;
    f4 vxy = xr0 * yr0 + xr1 * yr1 + xr2 * yr2;
    f4 vxx = xr0 * xr0 + xr1 * xr1 + xr2 * xr2;
    f4 Sx = hsum3(vx), Sy = hsum3(vy), Sxy = hsum3(vxy), Sxx = hsum3(vxx);
    f4 A, B;
#pragma unroll
    for (int j = 0; j < 4; ++j) {
      float num = 9.0f * Sxy[j] - Sx[j] * Sy[j];
      float den = 9.0f * Sxx[j] - Sx[j] * Sx[j] + 8.1e-05f;  // >0 (Cauchy-Schwarz)
      float rd;
      asm("v_rcp_f32 %0, %1" : "=v"(rd) : "v"(den));
      float a = num * rd;
      A[j] = a;
      B[j] = Sy[j] * inv9 - a * (Sx[j] * inv9);
    }
    if (leftE) {  // A(-1) := A(0): lane0 elem3 <- lane1 elem0
      float ta = __shfl_down(A[0], 1), tb = __shfl_down(B[0], 1);
      if (lane == 0) { A[3] = ta; B[3] = tb; }
    }
    if (rightE) {  // A(W) := A(W-1): lane63 elem0 <- lane62 elem3
      float ta = __shfl_up(A[3], 1), tb = __shfl_up(B[3], 1);
      if (lane == 63) { A[0] = ta; B[0] = tb; }
    }
    f4 hAn = hsum3(A), hBn = hsum3(B);
    hA0 = hA1; hA1 = hA2; hA2 = hA3; hA3 = hAn;
    hB0 = hB1; hB1 = hB2; hB2 = hB3; hB3 = hBn;
    if (doemit) emit_row(ly, xr0);
  };

  // ---- prologue: prime rolling window ----
  {
    int cy0 = max(ty0 - 1, 0);   // center row of step 0
    int ra = max(cy0 - 1, 0);
    ldrow(ra, xr1, yr1);
    ldrow(cy0, xr2, yr2);
    nextr = min(cy0 + 1, H - 1);
    ldrow(nextr, xpf, ypf);
    nextr = min(nextr + 1, H - 1);
  }
  hA0 = hA1 = hA2 = hA3 = (f4)(0.0f);
  hB0 = hB1 = hB2 = hB3 = (f4)(0.0f);

  // ly=0: always advances (computes A-row ty0-1, replicated at top)
  step_adv(0, false, true);
  // ly=1: top strips re-use the same window (center row stuck at 0)
  if (ty0 == 0) dup_hist();
  else step_adv(1, false, true);
  // ly=2..TH: regular advancing+emitting steps (branch-free, renaming-clean)
#pragma unroll 4
  for (int ly = 2; ly <= TH; ++ly) step_adv(ly, true, true);
  // ly=TH+1: bottom strip duplicates the last A-row; others advance normally
  if (ty0 == H - TH) {
    dup_hist();
    emit_row(TH + 1, xr1);  // output row H-1: x comes from window center
  } else {
    step_adv(TH + 1, true, false);
  }
}

extern "C" void kernel_launch(void* const* d_in, const int* in_sizes, int n_in,
                              void* d_out, int out_size, void* d_ws, size_t ws_size,
                              hipStream_t stream) {
  const float* x = (const float*)d_in[0];
  const float* y = (const float*)d_in[1];
  float* out = (float*)d_out;
  const int H = 1024, W = 1024;
  const int imgs = in_sizes[0] / (H * W);  // 8*3 = 24
  dim3 block(64, 4, 1);
  dim3 grid((W + OWPB - 1) / OWPB, H / (TH * 4), imgs);
  gf_kernel<<<grid, block, 0, stream>>>(x, y, out, H, W);
}

// Round 3
// 248.587 us; speedup vs baseline: 1.1950x; 1.0734x over previous
//
#include <hip/hip_runtime.h>

// Guided filter, R=1, EPS=1e-6, (8,3,1024,1024) fp32 — shuffle-free streaming.
//
// One wave = 256 output cols (64 lanes x float4), TH=16 output rows.
// Each lane loads its own 8-col window (o0-2 .. o0+5) per row:
//   aligned dwordx4 (o0..o0+3) + dwordx2 (o0-2,o0-1) + dwordx2 (o0+4,o0+5)
// -> vertical 3-sums on 8 cols -> A,b on 6 cols -> horizontal 3-sum of A,b
// fully IN-REGISTER: zero cross-lane ops, pure-VALU dependency chain.
// Rolling 3-row register window + 1-step prefetch: loads never sit in the chain.
// Replication pad: clamped row indices (vertical, via history-dup steps at
// top/bottom) and per-lane clamped column loads + in-lane A/b copy at image
// left/right edges (A(-1) := A(0), A(W) := A(W-1)).

typedef float f4 __attribute__((ext_vector_type(4)));
typedef float f2 __attribute__((ext_vector_type(2)));

#define TH 16    // output rows per wave-strip
#define OW 256   // output cols per wave

struct Row { f2 xl; f4 xm; f2 xr; f2 yl; f4 ym; f2 yr; };

__global__ __launch_bounds__(256) void gf_kernel(
    const float* __restrict__ xg, const float* __restrict__ yg,
    float* __restrict__ outg, int H, int W) {
  const int lane = threadIdx.x;  // block = (64,4)
  const int img = blockIdx.z;
  const size_t ibase = (size_t)img * H * W;
  const float* __restrict__ xi = xg + ibase;
  const float* __restrict__ yi = yg + ibase;
  float* __restrict__ oi = outg + ibase;

  const int tx0 = blockIdx.x * OW;
  const int ty0 = (blockIdx.y * 4 + threadIdx.y) * TH;
  const int o0 = tx0 + 4 * lane;        // this lane's 4 output cols: o0..o0+3
  const bool fixl = (o0 == 0);          // lane owns image left edge
  const bool fixr = (o0 == W - 4);      // lane owns image right edge
  const int olo = fixl ? 0 : (o0 - 2);  // 8B-aligned
  const int ohi = fixr ? (W - 2) : (o0 + 4);
  const float inv9 = 1.0f / 9.0f;

  Row r0, r1, r2, pf;                   // rolling rows + prefetch
  f4 hA0, hA1, hA2, hA3, hB0, hB1, hB2, hB3;  // 4-slot history (renaming-clean)
  int nextr;

  auto ldrow = [&](int rr, Row& R) {
    const float* xr = xi + (size_t)rr * W;
    const float* yr = yi + (size_t)rr * W;
    R.xm = *(const f4*)(xr + o0);
    R.xl = *(const f2*)(xr + olo);
    R.xr = *(const f2*)(xr + ohi);
    R.ym = *(const f4*)(yr + o0);
    R.yl = *(const f2*)(yr + olo);
    R.yr = *(const f2*)(yr + ohi);
    if (fixl) { R.xl[1] = R.xl[0]; R.yl[1] = R.yl[0]; }  // cols -2,-1 -> col 0
    if (fixr) { R.xr[0] = R.xr[1]; R.yr[0] = R.yr[1]; }  // cols W,W+1 -> col W-1
  };

  auto emit_row = [&](int ly, f4 xv) {
    f4 SA = hA1 + hA2 + hA3;
    f4 SB = hB1 + hB2 + hB3;
    f4 st;
#pragma unroll
    for (int j = 0; j < 4; ++j) {
      float res = (SA[j] * xv[j] + SB[j]) * inv9;
      float t = truncf(res);
      st[j] = fminf(fmaxf(t, 0.0f), 255.0f);
    }
    int gr = ty0 + ly - 2;
    __builtin_nontemporal_store(st, (f4*)(oi + (size_t)gr * W + o0));
  };

  auto dup_hist = [&]() {  // push duplicate of newest A,b row (replication)
    hA0 = hA1; hA1 = hA2; hA2 = hA3;
    hB0 = hB1; hB1 = hB2; hB2 = hB3;
  };

  auto step_adv = [&](int ly, bool doemit, bool dopf) {
    r0 = r1; r1 = r2; r2 = pf;
    if (dopf) {
      ldrow(nextr, pf);
      nextr = min(nextr + 1, H - 1);
    }
    // vertical 3-sums on 8 cols (l:2, m:4, r:2)
    f2 vxl = r0.xl + r1.xl + r2.xl;
    f4 vxm = r0.xm + r1.xm + r2.xm;
    f2 vxr = r0.xr + r1.xr + r2.xr;
    f2 vyl = r0.yl + r1.yl + r2.yl;
    f4 vym = r0.ym + r1.ym + r2.ym;
    f2 vyr = r0.yr + r1.yr + r2.yr;
    f2 vxyl = r0.xl * r0.yl + r1.xl * r1.yl + r2.xl * r2.yl;
    f4 vxym = r0.xm * r0.ym + r1.xm * r1.ym + r2.xm * r2.ym;
    f2 vxyr = r0.xr * r0.yr + r1.xr * r1.yr + r2.xr * r2.yr;
    f2 vxxl = r0.xl * r0.xl + r1.xl * r1.xl + r2.xl * r2.xl;
    f4 vxxm = r0.xm * r0.xm + r1.xm * r1.xm + r2.xm * r2.xm;
    f2 vxxr = r0.xr * r0.xr + r1.xr * r1.xr + r2.xr * r2.xr;
    // 8-col views (index i = image col o0-2+i)
    float vx[8]  = {vxl[0],  vxl[1],  vxm[0],  vxm[1],  vxm[2],  vxm[3],  vxr[0],  vxr[1]};
    float vy[8]  = {vyl[0],  vyl[1],  vym[0],  vym[1],  vym[2],  vym[3],  vyr[0],  vyr[1]};
    float vxy[8] = {vxyl[0], vxyl[1], vxym[0], vxym[1], vxym[2], vxym[3], vxyr[0], vxyr[1]};
    float vxx[8] = {vxxl[0], vxxl[1], vxxm[0], vxxm[1], vxxm[2], vxxm[3], vxxr[0], vxxr[1]};
    // A,b for 6 cols (A[j] = col o0-1+j), all in-register
    float A[6], B[6];
#pragma unroll
    for (int j = 0; j < 6; ++j) {
      float Sx  = vx[j] + vx[j + 1] + vx[j + 2];
      float Sy  = vy[j] + vy[j + 1] + vy[j + 2];
      float Sxy = vxy[j] + vxy[j + 1] + vxy[j + 2];
      float Sxx = vxx[j] + vxx[j + 1] + vxx[j + 2];
      float num = 9.0f * Sxy - Sx * Sy;
      float den = 9.0f * Sxx - Sx * Sx + 8.1e-05f;  // >0 (Cauchy-Schwarz)
      float rd;
      asm("v_rcp_f32 %0, %1" : "=v"(rd) : "v"(den));
      float a = num * rd;
      A[j] = a;
      B[j] = Sy * inv9 - a * (Sx * inv9);
    }
    // image-edge replication of A,b (in-lane, no shuffle)
    if (fixl) { A[0] = A[1]; B[0] = B[1]; }
    if (fixr) { A[5] = A[4]; B[5] = B[4]; }
    // horizontal 3-sum of A,b for the 4 output cols
    f4 hAn, hBn;
#pragma unroll
    for (int j = 0; j < 4; ++j) {
      hAn[j] = A[j] + A[j + 1] + A[j + 2];
      hBn[j] = B[j] + B[j + 1] + B[j + 2];
    }
    hA0 = hA1; hA1 = hA2; hA2 = hA3; hA3 = hAn;
    hB0 = hB1; hB1 = hB2; hB2 = hB3; hB3 = hBn;
    if (doemit) emit_row(ly, r0.xm);
  };

  // ---- prologue: prime rolling window ----
  {
    int cy0 = max(ty0 - 1, 0);  // center row of step 0
    int ra = max(cy0 - 1, 0);
    ldrow(ra, r1);
    ldrow(cy0, r2);
    nextr = min(cy0 + 1, H - 1);
    ldrow(nextr, pf);
    nextr = min(nextr + 1, H - 1);
  }
  hA0 = hA1 = hA2 = hA3 = (f4)(0.0f);
  hB0 = hB1 = hB2 = hB3 = (f4)(0.0f);

  // ly=0: computes A-row ty0-1 (top strips: replicated row, window clamps)
  step_adv(0, false, true);
  // ly=1: top strips duplicate (center row stuck at 0); others advance
  if (ty0 == 0) dup_hist();
  else step_adv(1, false, true);
  // ly=2..TH: regular advancing+emitting steps
#pragma unroll 4
  for (int ly = 2; ly <= TH; ++ly) step_adv(ly, true, true);
  // ly=TH+1: bottom strip duplicates last A-row; others advance normally
  if (ty0 == H - TH) {
    dup_hist();
    emit_row(TH + 1, r1.xm);  // output row H-1: x from window center
  } else {
    step_adv(TH + 1, true, false);
  }
}

extern "C" void kernel_launch(void* const* d_in, const int* in_sizes, int n_in,
                              void* d_out, int out_size, void* d_ws, size_t ws_size,
                              hipStream_t stream) {
  const float* x = (const float*)d_in[0];
  const float* y = (const float*)d_in[1];
  float* out = (float*)d_out;
  const int H = 1024, W = 1024;
  const int imgs = in_sizes[0] / (H * W);  // 8*3 = 24
  dim3 block(64, 4, 1);
  dim3 grid(W / OW, H / (TH * 4), imgs);
  gf_kernel<<<grid, block, 0, stream>>>(x, y, out, H, W);
}